// Round 6
// baseline (2845.870 us; speedup 1.0000x reference)
//
#include <hip/hip_runtime.h>
#include <hip/hip_bf16.h>

typedef __hip_bfloat16 bf16;

__device__ __forceinline__ float lrelu(float a) { return a > 0.f ? a : 0.2f * a; }
__device__ __forceinline__ int clampi(int v, int hi) { return v < 0 ? 0 : (v >= hi ? hi - 1 : v); }
// load external float tensor element: fp32 or bf16 per runtime flag
__device__ __forceinline__ float ldx(const void* p, size_t i, int f32) {
  return f32 ? ((const float*)p)[i] : (float)((const bf16*)p)[i];
}
__device__ __forceinline__ float4 ldx4(const void* p, size_t i, int f32) {
  if (f32) return *(const float4*)((const float*)p + i);
  const __hip_bfloat162* q = (const __hip_bfloat162*)((const bf16*)p + i);
  float2 a = __bfloat1622float2(q[0]), b = __bfloat1622float2(q[1]);
  return make_float4(a.x, a.y, b.x, b.y);
}

// ---------------- runtime dtype detection ----------------
// flags[0] = 1 if edge_index is int64; flags[1] = 1 if float tensors are fp32
__global__ __launch_bounds__(256) void detect_k(const int* __restrict__ ei32,
                                                const unsigned short* __restrict__ xw, int E,
                                                int* __restrict__ flags) {
  __shared__ int s64, sf;
  int t = threadIdx.x;
  if (t == 0) { s64 = 1; sf = 0; }
  __syncthreads();
  int lim = E < 2048 ? E : 2048;
  for (int k = t; k < lim; k += 256)
    if (ei32[2 * k + 1] != 0) atomicAnd(&s64, 0);
  int hit = 0;
  for (int k = t; k < 4096; k += 256) {
    int ex = (xw[k] >> 7) & 0xFF;
    if (ex >= 0xC3) hit = 1;  // |value| >= 2^68 as bf16: impossible for real data
  }
  if (hit) atomicOr(&sf, 1);
  __syncthreads();
  if (t == 0) { flags[0] = s64; flags[1] = sf; }
}

// ---------------- CSR build ----------------
__global__ __launch_bounds__(256) void count_k(const int* __restrict__ ei32, int E, int N,
                                               const int* __restrict__ flags,
                                               int* __restrict__ cnt) {
  int e = blockIdx.x * blockDim.x + threadIdx.x;
  if (e >= E) return;
  int is64 = flags[0] != 0;
  int d = is64 ? ei32[2 * ((size_t)E + e)] : ei32[(size_t)E + e];
  atomicAdd(&cnt[clampi(d, N)], 1);
}

__global__ __launch_bounds__(1024) void scan1_k(const int* __restrict__ cnt, int* __restrict__ excl,
                                                int* __restrict__ bsum, int n) {
  __shared__ int sh[1024];
  int i = blockIdx.x * 1024 + threadIdx.x;
  int v = (i < n) ? cnt[i] : 0;
  sh[threadIdx.x] = v;
  __syncthreads();
  for (int off = 1; off < 1024; off <<= 1) {
    int t = (threadIdx.x >= off) ? sh[threadIdx.x - off] : 0;
    __syncthreads();
    sh[threadIdx.x] += t;
    __syncthreads();
  }
  if (i < n) excl[i] = sh[threadIdx.x] - v;
  if (threadIdx.x == 1023) bsum[blockIdx.x] = sh[1023];
}

__global__ __launch_bounds__(128) void scan2_k(int* bsum, int nb) {
  __shared__ int sh[128];
  int t = threadIdx.x;
  int v = (t < nb) ? bsum[t] : 0;
  sh[t] = v;
  __syncthreads();
  for (int off = 1; off < 128; off <<= 1) {
    int x = (t >= off) ? sh[t - off] : 0;
    __syncthreads();
    sh[t] += x;
    __syncthreads();
  }
  if (t < nb) bsum[t] = sh[t] - v;
}

__global__ __launch_bounds__(256) void scan3_k(int* __restrict__ row_ptr,
                                               const int* __restrict__ bsum,
                                               int* __restrict__ cur, int n, int E) {
  int i = blockIdx.x * blockDim.x + threadIdx.x;
  if (i < n) {
    int r = row_ptr[i] + bsum[i >> 10];
    row_ptr[i] = r;
    cur[i] = r;
  }
  if (i == 0) row_ptr[n] = E;
}

// wvec_l = We_l @ att_e_l  (3x 16-vector)
__global__ __launch_bounds__(64) void wvec_k(const void* We1, const void* ae1, const void* We2,
                                             const void* ae2, const void* We3, const void* ae3,
                                             const int* __restrict__ flags, float* wv) {
  int t = threadIdx.x;
  if (t >= 48) return;
  int f32 = flags[1];
  int l = t >> 4, j = t & 15;
  const void* We = l == 0 ? We1 : (l == 1 ? We2 : We3);
  const void* ae = l == 0 ? ae1 : (l == 1 ? ae2 : ae3);
  int C = l == 0 ? 64 : (l == 1 ? 32 : 16);
  float s = 0.f;
  for (int c = 0; c < C; ++c) s += ldx(We, (size_t)j * C + c, f32) * ldx(ae, c, f32);
  wv[l * 16 + j] = s;
}

// scatter edges into dst-sorted order; per-edge scalars q1,q2,q3 (fp32)
__global__ __launch_bounds__(256) void scatter_k(const int* __restrict__ ei32, const void* eattr,
                                                 const float* __restrict__ wv,
                                                 const int* __restrict__ flags,
                                                 int* __restrict__ cur, int* __restrict__ src_sorted,
                                                 float* __restrict__ q1s, float* __restrict__ q2s,
                                                 float* __restrict__ q3s, int E, int N) {
  __shared__ float w[48];
  if (threadIdx.x < 48) w[threadIdx.x] = wv[threadIdx.x];
  __syncthreads();
  int e = blockIdx.x * 256 + threadIdx.x;
  if (e >= E) return;
  int is64 = flags[0] != 0, f32 = flags[1] != 0;
  int s = is64 ? ei32[2 * (size_t)e] : ei32[e];
  int d = is64 ? ei32[2 * ((size_t)E + e)] : ei32[(size_t)E + e];
  s = clampi(s, N);
  d = clampi(d, N);
  float v[16];
  if (f32) {
    const float4* p = (const float4*)((const float*)eattr + (size_t)e * 16);
#pragma unroll
    for (int j = 0; j < 4; ++j) {
      float4 t = p[j];
      v[4 * j] = t.x; v[4 * j + 1] = t.y; v[4 * j + 2] = t.z; v[4 * j + 3] = t.w;
    }
  } else {
    const __hip_bfloat162* p = (const __hip_bfloat162*)((const bf16*)eattr + (size_t)e * 16);
#pragma unroll
    for (int j = 0; j < 8; ++j) {
      float2 t = __bfloat1622float2(p[j]);
      v[2 * j] = t.x; v[2 * j + 1] = t.y;
    }
  }
  float q1 = 0.f, q2 = 0.f, q3 = 0.f;
#pragma unroll
  for (int j = 0; j < 16; ++j) {
    q1 += v[j] * w[j];
    q2 += v[j] * w[16 + j];
    q3 += v[j] * w[32 + j];
  }
  int pos = clampi(atomicAdd(&cur[d], 1), E);
  src_sorted[pos] = s;
  q1s[pos] = q1;
  q2s[pos] = q2;
  q3s[pos] = q3;
}

// ---------------- per-layer: h = X @ W, register-blocked tiled GEMM ----------------
// K = 2*C. Each thread: 4 nodes x 8 cols. W fully in LDS; X staged per 32-k
// chunk, transposed [k][node] with XOR-swizzled node-quads (conflict-free
// ds_read_b128). Fused as/ad epilogue via cg-subgroup shfl reduce.
template <int K, int C, bool XEXT>
__global__ __launch_bounds__(256) void mm2_k(const void* Xv, const void* Wv, const void* ats_v,
                                             const void* atd_v, const int* __restrict__ flags,
                                             int N, float* __restrict__ h, float* __restrict__ as_,
                                             float* __restrict__ ad_) {
  static_assert(K == 2 * C, "");
  constexpr int NCG = C / 8;      // col-groups per node (8/4/2)
  constexpr int TM = 1024 / NCG;  // nodes per block (128/256/512)
  __shared__ float Wl[K * C];
  __shared__ float Xl[32 * TM];
  const int f32 = flags[1];
  const int tid = threadIdx.x;
  for (int i = tid; i < K * C; i += 256) Wl[i] = ldx(Wv, i, f32);
  const int cg = tid & (NCG - 1);
  const int ng = tid / NCG;  // 0 .. TM/4-1
  const int c0 = cg * 8;
  float ats[8], atd[8];
#pragma unroll
  for (int j = 0; j < 8; ++j) {
    ats[j] = ldx(ats_v, c0 + j, f32);
    atd[j] = ldx(atd_v, c0 + j, f32);
  }
  const int n_base = blockIdx.x * TM;
  float acc[4][8];
#pragma unroll
  for (int i = 0; i < 4; ++i)
#pragma unroll
    for (int j = 0; j < 8; ++j) acc[i][j] = 0.f;

#pragma unroll
  for (int kc = 0; kc < K / 32; ++kc) {
    __syncthreads();
    // stage X chunk: global row-major -> LDS [k][node^swizzle]
#pragma unroll
    for (int t = 0; t < TM / 32; ++t) {
      int f = tid + t * 256;
      int node = f >> 3, kq = f & 7;
      int gn = n_base + node;
      if (gn >= N) gn = N - 1;
      float4 v;
      if (XEXT)
        v = ldx4(Xv, (size_t)gn * K + kc * 32 + kq * 4, f32);
      else
        v = *(const float4*)((const float*)Xv + (size_t)gn * K + kc * 32 + kq * 4);
      int col = node ^ (kq * 4);  // quad-preserving XOR swizzle
      Xl[(kq * 4 + 0) * TM + col] = v.x;
      Xl[(kq * 4 + 1) * TM + col] = v.y;
      Xl[(kq * 4 + 2) * TM + col] = v.z;
      Xl[(kq * 4 + 3) * TM + col] = v.w;
    }
    __syncthreads();
#pragma unroll
    for (int kk = 0; kk < 32; ++kk) {
      const float4 xv = *(const float4*)&Xl[kk * TM + ((ng * 4) ^ ((kk >> 2) * 4))];
      const float4 w0 = *(const float4*)&Wl[(kc * 32 + kk) * C + c0];
      const float4 w1 = *(const float4*)&Wl[(kc * 32 + kk) * C + c0 + 4];
      const float xs[4] = {xv.x, xv.y, xv.z, xv.w};
      const float ws[8] = {w0.x, w0.y, w0.z, w0.w, w1.x, w1.y, w1.z, w1.w};
#pragma unroll
      for (int i = 0; i < 4; ++i)
#pragma unroll
        for (int j = 0; j < 8; ++j) acc[i][j] += xs[i] * ws[j];
    }
  }
  // epilogue: store h, fused as/ad reduction over the NCG col-groups
#pragma unroll
  for (int i = 0; i < 4; ++i) {
    int n = n_base + ng * 4 + i;
    float vs = 0.f, vd = 0.f;
#pragma unroll
    for (int j = 0; j < 8; ++j) {
      vs += acc[i][j] * ats[j];
      vd += acc[i][j] * atd[j];
    }
#pragma unroll
    for (int off = NCG / 2; off > 0; off >>= 1) {
      vs += __shfl_xor(vs, off, NCG);
      vd += __shfl_xor(vd, off, NCG);
    }
    if (n < N) {
      float* hr = &h[(size_t)n * C + c0];
      *(float4*)hr = make_float4(acc[i][0], acc[i][1], acc[i][2], acc[i][3]);
      *(float4*)(hr + 4) = make_float4(acc[i][4], acc[i][5], acc[i][6], acc[i][7]);
      if (cg == 0) {
        as_[n] = vs;
        ad_[n] = vd;
      }
    }
  }
}

// ---------------- per-layer: online-softmax aggregation ----------------
template <int C, bool ELU, bool LAST>
__global__ __launch_bounds__(256) void agg_k(const int* __restrict__ row_ptr,
                                             const int* __restrict__ src_sorted,
                                             const float* __restrict__ qs,
                                             const float* __restrict__ as_,
                                             const float* __restrict__ ad_,
                                             const float* __restrict__ h, const void* b,
                                             const int* __restrict__ flags, void* out, int N,
                                             int E) {
  const int GR = 256 / C;
  int lane = threadIdx.x & (C - 1);
  int grp = threadIdx.x / C;
  int f32 = flags[1];
  float bc = ldx(b, lane, f32);
  for (int n = blockIdx.x * GR + grp; n < N; n += gridDim.x * GR) {
    int start = row_ptr[n], end = row_ptr[n + 1];
    int deg = end > start ? end - start : 0;
    // mean of incoming q == self-loop edge-attr score (fill_value='mean')
    float qsum = 0.f;
    for (int j = lane; j < deg; j += C) qsum += qs[start + j];
#pragma unroll
    for (int off = C / 2; off > 0; off >>= 1) qsum += __shfl_xor(qsum, off, C);
    float qloop = qsum / fmaxf((float)deg, 1.0f);
    float adn = ad_[n];
    float m = lrelu(as_[n] + adn + qloop), den = 1.0f;
    float acc = h[(size_t)n * C + lane];
    for (int j = 0; j < deg; ++j) {
      int s = clampi(src_sorted[start + j], N);        // broadcast load
      float aj = lrelu(as_[s] + adn + qs[start + j]);  // broadcast loads
      float nm = fmaxf(m, aj);
      float sc = __expf(m - nm);
      float p = __expf(aj - nm);
      den = den * sc + p;
      acc = acc * sc + p * h[(size_t)s * C + lane];  // coalesced row read
      m = nm;
    }
    float o = acc / (den + 1e-16f) + bc;
    if (ELU) o = o > 0.f ? o : (__expf(o) - 1.0f);
    if (LAST && !f32)
      ((bf16*)out)[(size_t)n * C + lane] = (bf16)o;
    else
      ((float*)out)[(size_t)n * C + lane] = o;
  }
}

extern "C" void kernel_launch(void* const* d_in, const int* in_sizes, int n_in, void* d_out,
                              int out_size, void* d_ws, size_t ws_size, hipStream_t stream) {
  const void* x = d_in[0];
  const int* ei32 = (const int*)d_in[1];
  void* eattr = d_in[2];  // dead after scatter_k; reusable as scratch (inputs restored each launch)
  const void *W1 = d_in[3], *s1 = d_in[4], *t1 = d_in[5], *We1 = d_in[6], *ae1 = d_in[7],
             *b1 = d_in[8];
  const void *W2 = d_in[9], *s2 = d_in[10], *t2 = d_in[11], *We2 = d_in[12], *ae2 = d_in[13],
             *b2 = d_in[14];
  const void *W3 = d_in[15], *s3 = d_in[16], *t3 = d_in[17], *We3 = d_in[18], *ae3 = d_in[19],
             *b3 = d_in[20];

  const int N = in_sizes[0] / 128;
  const int E = in_sizes[1] / 2;

  // Workspace layout (~27.6 MB + optional 51.2 MB). Index-critical buffers first.
  char* p = (char*)d_ws;
  auto alloc = [&](size_t bytes) -> void* {
    void* r = (void*)p;
    p += (bytes + 255) & ~(size_t)255;
    return r;
  };
  int* row_ptr = (int*)alloc((size_t)(N + 1) * 4);
  int* src_sorted = (int*)alloc((size_t)E * 4);
  int* cnt = (int*)alloc((size_t)N * 4);
  int* cur = (int*)alloc((size_t)N * 4);
  int* bsum = (int*)alloc(128 * 4);
  float* wv = (float*)alloc(64 * 4);
  int* flags = (int*)alloc(256);
  float* as_ = (float*)alloc((size_t)N * 4);
  float* ad_ = (float*)alloc((size_t)N * 4);
  float* q1s = (float*)alloc((size_t)E * 4);
  float* q2s = (float*)alloc((size_t)E * 4);
  float* q3s = (float*)alloc((size_t)E * 4);
  size_t used = (size_t)(p - (char*)d_ws);
  size_t need = 2 * ((size_t)N * 64 * 4 + 256);
  float *bufH, *bufO;
  if (used + need <= ws_size) {
    bufH = (float*)alloc((size_t)N * 64 * 4);
    bufO = (float*)alloc((size_t)N * 64 * 4);
  } else {
    bufH = (float*)eattr;
    bufO = (float*)eattr + (size_t)N * 64;
  }

  // ---- detection + CSR build ----
  hipMemsetAsync(cnt, 0, (size_t)N * 4, stream);
  detect_k<<<1, 256, 0, stream>>>(ei32, (const unsigned short*)x, E, flags);
  count_k<<<(E + 255) / 256, 256, 0, stream>>>(ei32, E, N, flags, cnt);
  int nb = (N + 1023) / 1024;
  scan1_k<<<nb, 1024, 0, stream>>>(cnt, row_ptr, bsum, N);
  scan2_k<<<1, 128, 0, stream>>>(bsum, nb);
  scan3_k<<<(N + 255) / 256, 256, 0, stream>>>(row_ptr, bsum, cur, N, E);
  wvec_k<<<1, 64, 0, stream>>>(We1, ae1, We2, ae2, We3, ae3, flags, wv);
  scatter_k<<<(E + 255) / 256, 256, 0, stream>>>(ei32, eattr, wv, flags, cur, src_sorted, q1s, q2s,
                                                 q3s, E, N);

  // ---- layer 1: 128 -> 64 ----
  mm2_k<128, 64, true><<<(N + 127) / 128, 256, 0, stream>>>(x, W1, s1, t1, flags, N, bufH, as_,
                                                            ad_);
  agg_k<64, true, false><<<(N + 3) / 4, 256, 0, stream>>>(row_ptr, src_sorted, q1s, as_, ad_, bufH,
                                                          b1, flags, bufO, N, E);
  // ---- layer 2: 64 -> 32 ----
  mm2_k<64, 32, false><<<(N + 255) / 256, 256, 0, stream>>>(bufO, W2, s2, t2, flags, N, bufH, as_,
                                                            ad_);
  agg_k<32, true, false><<<(N + 7) / 8, 256, 0, stream>>>(row_ptr, src_sorted, q2s, as_, ad_, bufH,
                                                          b2, flags, bufO, N, E);
  // ---- layer 3: 32 -> 16 ----
  mm2_k<32, 16, false><<<(N + 511) / 512, 256, 0, stream>>>(bufO, W3, s3, t3, flags, N, bufH, as_,
                                                            ad_);
  agg_k<16, false, true><<<(N + 15) / 16, 256, 0, stream>>>(row_ptr, src_sorted, q3s, as_, ad_,
                                                            bufH, b3, flags, d_out, N, E);
}

// Round 7
// 820.120 us; speedup vs baseline: 3.4701x; 3.4701x over previous
//
#include <hip/hip_runtime.h>
#include <hip/hip_bf16.h>

typedef __hip_bfloat16 bf16;

__device__ __forceinline__ float lrelu(float a) { return a > 0.f ? a : 0.2f * a; }
__device__ __forceinline__ int clampi(int v, int hi) { return v < 0 ? 0 : (v >= hi ? hi - 1 : v); }
// load external float tensor element: fp32 or bf16 per runtime flag
__device__ __forceinline__ float ldx(const void* p, size_t i, int f32) {
  return f32 ? ((const float*)p)[i] : (float)((const bf16*)p)[i];
}
__device__ __forceinline__ float4 ldx4(const void* p, size_t i, int f32) {
  if (f32) return *(const float4*)((const float*)p + i);
  const __hip_bfloat162* q = (const __hip_bfloat162*)((const bf16*)p + i);
  float2 a = __bfloat1622float2(q[0]), b = __bfloat1622float2(q[1]);
  return make_float4(a.x, a.y, b.x, b.y);
}

// ---------------- runtime dtype detection ----------------
// flags[0] = 1 if edge_index is int64; flags[1] = 1 if float tensors are fp32
__global__ __launch_bounds__(256) void detect_k(const int* __restrict__ ei32,
                                                const unsigned short* __restrict__ xw, int E,
                                                int* __restrict__ flags) {
  __shared__ int s64, sf;
  int t = threadIdx.x;
  if (t == 0) { s64 = 1; sf = 0; }
  __syncthreads();
  int lim = E < 2048 ? E : 2048;
  for (int k = t; k < lim; k += 256)
    if (ei32[2 * k + 1] != 0) atomicAnd(&s64, 0);
  int hit = 0;
  for (int k = t; k < 4096; k += 256) {
    int ex = (xw[k] >> 7) & 0xFF;
    if (ex >= 0xC3) hit = 1;  // |value| >= 2^68 as bf16: impossible for real data
  }
  if (hit) atomicOr(&sf, 1);
  __syncthreads();
  if (t == 0) { flags[0] = s64; flags[1] = sf; }
}

// ---------------- CSR build ----------------
__global__ __launch_bounds__(256) void count_k(const int* __restrict__ ei32, int E, int N,
                                               const int* __restrict__ flags,
                                               int* __restrict__ cnt) {
  int e = blockIdx.x * blockDim.x + threadIdx.x;
  if (e >= E) return;
  int is64 = flags[0] != 0;
  int d = is64 ? ei32[2 * ((size_t)E + e)] : ei32[(size_t)E + e];
  atomicAdd(&cnt[clampi(d, N)], 1);
}

__global__ __launch_bounds__(1024) void scan1_k(const int* __restrict__ cnt, int* __restrict__ excl,
                                                int* __restrict__ bsum, int n) {
  __shared__ int sh[1024];
  int i = blockIdx.x * 1024 + threadIdx.x;
  int v = (i < n) ? cnt[i] : 0;
  sh[threadIdx.x] = v;
  __syncthreads();
  for (int off = 1; off < 1024; off <<= 1) {
    int t = (threadIdx.x >= off) ? sh[threadIdx.x - off] : 0;
    __syncthreads();
    sh[threadIdx.x] += t;
    __syncthreads();
  }
  if (i < n) excl[i] = sh[threadIdx.x] - v;
  if (threadIdx.x == 1023) bsum[blockIdx.x] = sh[1023];
}

__global__ __launch_bounds__(128) void scan2_k(int* bsum, int nb) {
  __shared__ int sh[128];
  int t = threadIdx.x;
  int v = (t < nb) ? bsum[t] : 0;
  sh[t] = v;
  __syncthreads();
  for (int off = 1; off < 128; off <<= 1) {
    int x = (t >= off) ? sh[t - off] : 0;
    __syncthreads();
    sh[t] += x;
    __syncthreads();
  }
  if (t < nb) bsum[t] = sh[t] - v;
}

__global__ __launch_bounds__(256) void scan3_k(int* __restrict__ row_ptr,
                                               const int* __restrict__ bsum,
                                               int* __restrict__ cur, int n, int E) {
  int i = blockIdx.x * blockDim.x + threadIdx.x;
  if (i < n) {
    int r = row_ptr[i] + bsum[i >> 10];
    row_ptr[i] = r;
    cur[i] = r;
  }
  if (i == 0) row_ptr[n] = E;
}

// wvec_l = We_l @ att_e_l  (3x 16-vector)
__global__ __launch_bounds__(64) void wvec_k(const void* We1, const void* ae1, const void* We2,
                                             const void* ae2, const void* We3, const void* ae3,
                                             const int* __restrict__ flags, float* wv) {
  int t = threadIdx.x;
  if (t >= 48) return;
  int f32 = flags[1];
  int l = t >> 4, j = t & 15;
  const void* We = l == 0 ? We1 : (l == 1 ? We2 : We3);
  const void* ae = l == 0 ? ae1 : (l == 1 ? ae2 : ae3);
  int C = l == 0 ? 64 : (l == 1 ? 32 : 16);
  float s = 0.f;
  for (int c = 0; c < C; ++c) s += ldx(We, (size_t)j * C + c, f32) * ldx(ae, c, f32);
  wv[l * 16 + j] = s;
}

// scatter edges into dst-sorted order; per-edge scalars q1,q2,q3 (fp32)
__global__ __launch_bounds__(256) void scatter_k(const int* __restrict__ ei32, const void* eattr,
                                                 const float* __restrict__ wv,
                                                 const int* __restrict__ flags,
                                                 int* __restrict__ cur, int* __restrict__ src_sorted,
                                                 float* __restrict__ q1s, float* __restrict__ q2s,
                                                 float* __restrict__ q3s, int E, int N) {
  __shared__ float w[48];
  if (threadIdx.x < 48) w[threadIdx.x] = wv[threadIdx.x];
  __syncthreads();
  int e = blockIdx.x * 256 + threadIdx.x;
  if (e >= E) return;
  int is64 = flags[0] != 0, f32 = flags[1] != 0;
  int s = is64 ? ei32[2 * (size_t)e] : ei32[e];
  int d = is64 ? ei32[2 * ((size_t)E + e)] : ei32[(size_t)E + e];
  s = clampi(s, N);
  d = clampi(d, N);
  float v[16];
  if (f32) {
    const float4* p = (const float4*)((const float*)eattr + (size_t)e * 16);
#pragma unroll
    for (int j = 0; j < 4; ++j) {
      float4 t = p[j];
      v[4 * j] = t.x; v[4 * j + 1] = t.y; v[4 * j + 2] = t.z; v[4 * j + 3] = t.w;
    }
  } else {
    const __hip_bfloat162* p = (const __hip_bfloat162*)((const bf16*)eattr + (size_t)e * 16);
#pragma unroll
    for (int j = 0; j < 8; ++j) {
      float2 t = __bfloat1622float2(p[j]);
      v[2 * j] = t.x; v[2 * j + 1] = t.y;
    }
  }
  float q1 = 0.f, q2 = 0.f, q3 = 0.f;
#pragma unroll
  for (int j = 0; j < 16; ++j) {
    q1 += v[j] * w[j];
    q2 += v[j] * w[16 + j];
    q3 += v[j] * w[32 + j];
  }
  int pos = clampi(atomicAdd(&cur[d], 1), E);
  src_sorted[pos] = s;
  q1s[pos] = q1;
  q2s[pos] = q2;
  q3s[pos] = q3;
}

// ---------------- per-layer: h = X @ W, register-blocked tiled GEMM ----------------
// K = 2*C. Thread tile: 2 nodes x 8 cols (16 accs — pressure-capped, see round-6
// post-mortem: 4x8 tile + full unroll spilled at 256 VGPR -> 45x scratch traffic).
// W fully in LDS; X staged per 32-k chunk, transposed with quad-XOR swizzle
// (writes <=2-way conflict = free; reads broadcast). __launch_bounds__(256,4)
// caps VGPRs at 128.
template <int K, int C, bool XEXT>
__global__ __launch_bounds__(256, 4) void mm3_k(const void* Xv, const void* Wv, const void* ats_v,
                                                const void* atd_v, const int* __restrict__ flags,
                                                int N, float* __restrict__ h,
                                                float* __restrict__ as_, float* __restrict__ ad_) {
  static_assert(K == 2 * C, "");
  constexpr int NCG = C / 8;     // col-groups per node (8/4/2)
  constexpr int TM = 512 / NCG;  // nodes per block (64/128/256)
  __shared__ __align__(16) float Wl[K * C];
  __shared__ __align__(16) float Xl[32 * TM];
  const int f32 = flags[1];
  const int tid = threadIdx.x;
  for (int i = tid; i < K * C; i += 256) Wl[i] = ldx(Wv, i, f32);
  const int cg = tid & (NCG - 1);
  const int ng = tid / NCG;  // node-pair index, 0 .. TM/2-1
  const int c0 = cg * 8;
  float ats[8], atd[8];
#pragma unroll
  for (int j = 0; j < 8; ++j) {
    ats[j] = ldx(ats_v, c0 + j, f32);
    atd[j] = ldx(atd_v, c0 + j, f32);
  }
  const int n_base = blockIdx.x * TM;
  float acc[2][8];
#pragma unroll
  for (int i = 0; i < 2; ++i)
#pragma unroll
    for (int j = 0; j < 8; ++j) acc[i][j] = 0.f;

#pragma unroll 1  // do NOT unroll: keeps register pressure flat across k-chunks
  for (int kc = 0; kc < K / 32; ++kc) {
    __syncthreads();
    // stage X chunk: global row-major -> LDS [k][node ^ (4*(k>>2))]
#pragma unroll
    for (int t = 0; t < TM / 32; ++t) {
      int f = tid + t * 256;
      int node = f >> 3, kq = f & 7;
      int gn = n_base + node;
      if (gn >= N) gn = N - 1;
      float4 v;
      if (XEXT)
        v = ldx4(Xv, (size_t)gn * K + kc * 32 + kq * 4, f32);
      else
        v = *(const float4*)((const float*)Xv + (size_t)gn * K + kc * 32 + kq * 4);
      int col = node ^ (kq * 4);  // quad-preserving XOR swizzle
      Xl[(kq * 4 + 0) * TM + col] = v.x;
      Xl[(kq * 4 + 1) * TM + col] = v.y;
      Xl[(kq * 4 + 2) * TM + col] = v.z;
      Xl[(kq * 4 + 3) * TM + col] = v.w;
    }
    __syncthreads();
#pragma unroll 8
    for (int kk = 0; kk < 32; ++kk) {
      const float2 xv = *(const float2*)&Xl[kk * TM + ((2 * ng) ^ ((kk >> 2) * 4))];
      const float4 w0 = *(const float4*)&Wl[(kc * 32 + kk) * C + c0];
      const float4 w1 = *(const float4*)&Wl[(kc * 32 + kk) * C + c0 + 4];
      const float ws[8] = {w0.x, w0.y, w0.z, w0.w, w1.x, w1.y, w1.z, w1.w};
#pragma unroll
      for (int j = 0; j < 8; ++j) {
        acc[0][j] += xv.x * ws[j];
        acc[1][j] += xv.y * ws[j];
      }
    }
  }
  // epilogue: store h, fused as/ad reduction over the NCG col-groups
#pragma unroll
  for (int i = 0; i < 2; ++i) {
    int n = n_base + ng * 2 + i;
    float vs = 0.f, vd = 0.f;
#pragma unroll
    for (int j = 0; j < 8; ++j) {
      vs += acc[i][j] * ats[j];
      vd += acc[i][j] * atd[j];
    }
#pragma unroll
    for (int off = NCG / 2; off > 0; off >>= 1) {
      vs += __shfl_xor(vs, off, NCG);
      vd += __shfl_xor(vd, off, NCG);
    }
    if (n < N) {
      float* hr = &h[(size_t)n * C + c0];
      *(float4*)hr = make_float4(acc[i][0], acc[i][1], acc[i][2], acc[i][3]);
      *(float4*)(hr + 4) = make_float4(acc[i][4], acc[i][5], acc[i][6], acc[i][7]);
      if (cg == 0) {
        as_[n] = vs;
        ad_[n] = vd;
      }
    }
  }
}

// ---------------- per-layer: online-softmax aggregation ----------------
template <int C, bool ELU, bool LAST>
__global__ __launch_bounds__(256) void agg_k(const int* __restrict__ row_ptr,
                                             const int* __restrict__ src_sorted,
                                             const float* __restrict__ qs,
                                             const float* __restrict__ as_,
                                             const float* __restrict__ ad_,
                                             const float* __restrict__ h, const void* b,
                                             const int* __restrict__ flags, void* out, int N,
                                             int E) {
  const int GR = 256 / C;
  int lane = threadIdx.x & (C - 1);
  int grp = threadIdx.x / C;
  int f32 = flags[1];
  float bc = ldx(b, lane, f32);
  for (int n = blockIdx.x * GR + grp; n < N; n += gridDim.x * GR) {
    int start = row_ptr[n], end = row_ptr[n + 1];
    int deg = end > start ? end - start : 0;
    // mean of incoming q == self-loop edge-attr score (fill_value='mean')
    float qsum = 0.f;
    for (int j = lane; j < deg; j += C) qsum += qs[start + j];
#pragma unroll
    for (int off = C / 2; off > 0; off >>= 1) qsum += __shfl_xor(qsum, off, C);
    float qloop = qsum / fmaxf((float)deg, 1.0f);
    float adn = ad_[n];
    float m = lrelu(as_[n] + adn + qloop), den = 1.0f;
    float acc = h[(size_t)n * C + lane];
    for (int j = 0; j < deg; ++j) {
      int s = clampi(src_sorted[start + j], N);        // broadcast load
      float aj = lrelu(as_[s] + adn + qs[start + j]);  // broadcast loads
      float nm = fmaxf(m, aj);
      float sc = __expf(m - nm);
      float p = __expf(aj - nm);
      den = den * sc + p;
      acc = acc * sc + p * h[(size_t)s * C + lane];  // coalesced row read
      m = nm;
    }
    float o = acc / (den + 1e-16f) + bc;
    if (ELU) o = o > 0.f ? o : (__expf(o) - 1.0f);
    if (LAST && !f32)
      ((bf16*)out)[(size_t)n * C + lane] = (bf16)o;
    else
      ((float*)out)[(size_t)n * C + lane] = o;
  }
}

extern "C" void kernel_launch(void* const* d_in, const int* in_sizes, int n_in, void* d_out,
                              int out_size, void* d_ws, size_t ws_size, hipStream_t stream) {
  const void* x = d_in[0];
  const int* ei32 = (const int*)d_in[1];
  void* eattr = d_in[2];  // dead after scatter_k; reusable as scratch (inputs restored each launch)
  const void *W1 = d_in[3], *s1 = d_in[4], *t1 = d_in[5], *We1 = d_in[6], *ae1 = d_in[7],
             *b1 = d_in[8];
  const void *W2 = d_in[9], *s2 = d_in[10], *t2 = d_in[11], *We2 = d_in[12], *ae2 = d_in[13],
             *b2 = d_in[14];
  const void *W3 = d_in[15], *s3 = d_in[16], *t3 = d_in[17], *We3 = d_in[18], *ae3 = d_in[19],
             *b3 = d_in[20];

  const int N = in_sizes[0] / 128;
  const int E = in_sizes[1] / 2;

  // Workspace layout (~27.6 MB + optional 51.2 MB). Index-critical buffers first.
  char* p = (char*)d_ws;
  auto alloc = [&](size_t bytes) -> void* {
    void* r = (void*)p;
    p += (bytes + 255) & ~(size_t)255;
    return r;
  };
  int* row_ptr = (int*)alloc((size_t)(N + 1) * 4);
  int* src_sorted = (int*)alloc((size_t)E * 4);
  int* cnt = (int*)alloc((size_t)N * 4);
  int* cur = (int*)alloc((size_t)N * 4);
  int* bsum = (int*)alloc(128 * 4);
  float* wv = (float*)alloc(64 * 4);
  int* flags = (int*)alloc(256);
  float* as_ = (float*)alloc((size_t)N * 4);
  float* ad_ = (float*)alloc((size_t)N * 4);
  float* q1s = (float*)alloc((size_t)E * 4);
  float* q2s = (float*)alloc((size_t)E * 4);
  float* q3s = (float*)alloc((size_t)E * 4);
  size_t used = (size_t)(p - (char*)d_ws);
  size_t need = 2 * ((size_t)N * 64 * 4 + 256);
  float *bufH, *bufO;
  if (used + need <= ws_size) {
    bufH = (float*)alloc((size_t)N * 64 * 4);
    bufO = (float*)alloc((size_t)N * 64 * 4);
  } else {
    bufH = (float*)eattr;
    bufO = (float*)eattr + (size_t)N * 64;
  }

  // ---- detection + CSR build ----
  hipMemsetAsync(cnt, 0, (size_t)N * 4, stream);
  detect_k<<<1, 256, 0, stream>>>(ei32, (const unsigned short*)x, E, flags);
  count_k<<<(E + 255) / 256, 256, 0, stream>>>(ei32, E, N, flags, cnt);
  int nb = (N + 1023) / 1024;
  scan1_k<<<nb, 1024, 0, stream>>>(cnt, row_ptr, bsum, N);
  scan2_k<<<1, 128, 0, stream>>>(bsum, nb);
  scan3_k<<<(N + 255) / 256, 256, 0, stream>>>(row_ptr, bsum, cur, N, E);
  wvec_k<<<1, 64, 0, stream>>>(We1, ae1, We2, ae2, We3, ae3, flags, wv);
  scatter_k<<<(E + 255) / 256, 256, 0, stream>>>(ei32, eattr, wv, flags, cur, src_sorted, q1s, q2s,
                                                 q3s, E, N);

  // ---- layer 1: 128 -> 64 ----
  mm3_k<128, 64, true><<<(N + 63) / 64, 256, 0, stream>>>(x, W1, s1, t1, flags, N, bufH, as_, ad_);
  agg_k<64, true, false><<<(N + 3) / 4, 256, 0, stream>>>(row_ptr, src_sorted, q1s, as_, ad_, bufH,
                                                          b1, flags, bufO, N, E);
  // ---- layer 2: 64 -> 32 ----
  mm3_k<64, 32, false><<<(N + 127) / 128, 256, 0, stream>>>(bufO, W2, s2, t2, flags, N, bufH, as_,
                                                            ad_);
  agg_k<32, true, false><<<(N + 7) / 8, 256, 0, stream>>>(row_ptr, src_sorted, q2s, as_, ad_, bufH,
                                                          b2, flags, bufO, N, E);
  // ---- layer 3: 32 -> 16 ----
  mm3_k<32, 16, false><<<(N + 255) / 256, 256, 0, stream>>>(bufO, W3, s3, t3, flags, N, bufH, as_,
                                                            ad_);
  agg_k<16, false, true><<<(N + 15) / 16, 256, 0, stream>>>(row_ptr, src_sorted, q3s, as_, ad_,
                                                            bufH, b3, flags, d_out, N, E);
}